// Round 8
// baseline (182.885 us; speedup 1.0000x reference)
//
#include <hip/hip_runtime.h>
#include <hip/hip_bf16.h>

// Problem constants: B=8, IN_C=64, H=W=32, NH=8, dkh=dvh=8, OUT_C=128.
// Inputs: float32 storage (verified R1/R2). Output: float32.
//
// R7->R8: k_attn was LDS-throughput-bound (4x b128/key = 51 us/CU of LDS pipe
// at measured 12 cyc/b128). Stage KV as packed bf16 (2x b128/key). Conv in
// k_out gets 2 cols/thread (halves per-FMA LDS traffic). k_prep sniff removed.

// ---- workspace layout (float32 element offsets) ----
constexpr int XPAD  = 0;                       // padded x: [8][64][34][34]
constexpr int NXPAD = 8 * 64 * 34 * 34;        // 591872
constexpr int WQKV  = NXPAD;                   // [192][64]        12288
constexpr int WCONV = WQKV + 12288;            // [64][64][9]      36864
constexpr int WATTN = WCONV + 36864;           // [64][64]          4096
constexpr int BQKV  = WATTN + 4096;            // 192
constexpr int BCONV = BQKV + 192;              // 64
constexpr int BATTN = BCONV + 64;              // 64
constexpr int RELW  = BATTN + 64;              // [63][8]           504
constexpr int RELH  = RELW + 504;              // [63][8]           504
constexpr int WEND  = RELH + 504;              // 646448
constexpr int QBUF  = WEND;                    // [64 bn][1024][8]  (q pre-scaled)
constexpr int KVBUF = QBUF + 524288;           // [64 bn][1024][16] (k|v interleaved)
constexpr int APRE  = KVBUF + 1048576;         // [8][64][1024]
// total = 2743600 floats = ~10.5 MB

__device__ __forceinline__ float dot8(float4 a, float4 b, const float* r) {
    return a.x*r[0] + a.y*r[1] + a.z*r[2] + a.w*r[3] +
           b.x*r[4] + b.y*r[5] + b.z*r[6] + b.w*r[7];
}

// RNE-pack two f32 into one dword of bf16 (lo = a, hi = b).
__device__ __forceinline__ unsigned int bfpack2(float a, float b) {
    unsigned int ua = __float_as_uint(a), ub = __float_as_uint(b);
    ua = (ua + 0x7fffu + ((ua >> 16) & 1u)) >> 16;
    ub = (ub + 0x7fffu + ((ub >> 16) & 1u)) >> 16;
    return ua | (ub << 16);
}
#define BFLO(u) __uint_as_float((u) << 16)
#define BFHI(u) __uint_as_float((u) & 0xffff0000u)

// ---------------------------------------------------------------------------
// Kernel 0: upcast all params (f32 passthrough) into ws; build padded x.
// ---------------------------------------------------------------------------
__global__ __launch_bounds__(256) void k_prep(
    const float* __restrict__ x,
    const float* __restrict__ conv_w,
    const float* __restrict__ conv_b,
    const float* __restrict__ qkv_w,
    const float* __restrict__ qkv_b,
    const float* __restrict__ attn_w,
    const float* __restrict__ attn_b,
    const float* __restrict__ rel_w,
    const float* __restrict__ rel_h,
    float* __restrict__ ws)
{
    int idx = blockIdx.x * 256 + threadIdx.x;
    if (idx < NXPAD) {
        int bc = idx / 1156, r = idx % 1156;
        int hh = r / 34 - 1, ww = r % 34 - 1;
        float v = 0.f;
        if ((unsigned)hh < 32u && (unsigned)ww < 32u)
            v = x[bc * 1024 + hh * 32 + ww];
        ws[XPAD + idx] = v;
    } else if (idx < WEND) {
        int w1 = idx - NXPAD;
        float v; int dst;
        if      (w1 < 12288) { v = qkv_w[w1];          dst = WQKV  + w1; }
        else if (w1 < 49152) { v = conv_w[w1 - 12288]; dst = WCONV + w1 - 12288; }
        else if (w1 < 53248) { v = attn_w[w1 - 49152]; dst = WATTN + w1 - 49152; }
        else if (w1 < 53440) { v = qkv_b[w1 - 53248];  dst = BQKV  + w1 - 53248; }
        else if (w1 < 53504) { v = conv_b[w1 - 53440]; dst = BCONV + w1 - 53440; }
        else if (w1 < 53568) { v = attn_b[w1 - 53504]; dst = BATTN + w1 - 53504; }
        else if (w1 < 54072) { v = rel_w[w1 - 53568];  dst = RELW  + w1 - 53568; }
        else                 { v = rel_h[w1 - 54072];  dst = RELH  + w1 - 54072; }
        ws[dst] = v;
    }
}

// ---------------------------------------------------------------------------
// Kernel 1: qkv 1x1 conv. grid = 8(b) x 4(pos chunk) x 16(out group of 12)
// = 512 blocks. Weight rows staged to LDS (coalesced), read as b128 broadcast.
// ---------------------------------------------------------------------------
__global__ __launch_bounds__(256) void k_qkv(
    const float* __restrict__ xpad,
    const float* __restrict__ wq,
    const float* __restrict__ bq,
    float* __restrict__ qbuf,
    float* __restrict__ kvbuf)
{
    __shared__ __align__(16) float4 wl4[192];   // 12 rows x 16 float4
    __shared__ float bl[12];

    int blk = blockIdx.x;
    int b = blk >> 6, rem = blk & 63, pc = rem >> 4, og = rem & 15;
    int tid = threadIdx.x;

    if (tid < 192) wl4[tid] = ((const float4*)(wq + og * 768))[tid];
    if (tid < 12)  bl[tid] = bq[og * 12 + tid];

    int p = pc * 256 + tid;                // 0..1023
    int h = p >> 5, w = p & 31;
    const float* xb = xpad + (b * 64) * 1156 + (h + 1) * 34 + (w + 1);
    float xr[64];
    #pragma unroll
    for (int c = 0; c < 64; ++c) xr[c] = xb[c * 1156];

    __syncthreads();

    #pragma unroll 4
    for (int oo = 0; oo < 12; ++oo) {
        int o = og * 12 + oo;              // 0..191
        float acc = bl[oo];
        #pragma unroll
        for (int c4 = 0; c4 < 16; ++c4) {
            float4 wv = wl4[oo * 16 + c4]; // uniform addr -> LDS broadcast
            acc = fmaf(wv.x, xr[c4 * 4 + 0], acc);
            acc = fmaf(wv.y, xr[c4 * 4 + 1], acc);
            acc = fmaf(wv.z, xr[c4 * 4 + 2], acc);
            acc = fmaf(wv.w, xr[c4 * 4 + 3], acc);
        }
        if (o < 64) {
            qbuf[((b * 8 + (o >> 3)) * 1024 + p) * 8 + (o & 7)] = acc * 0.35355339059327373f;
        } else if (o < 128) {
            int k = o - 64;
            kvbuf[((b * 8 + (k >> 3)) * 1024 + p) * 16 + (k & 7)] = acc;
        } else {
            int k = o - 128;
            kvbuf[((b * 8 + (k >> 3)) * 1024 + p) * 16 + 8 + (k & 7)] = acc;
        }
    }
}

// ---------------------------------------------------------------------------
// Kernel 2: attention. grid = 64(bn) x 8(query chunk of 128) = 512 blocks,
// 256 thr. Thread (lane, quad) handles queries {iq0, iq0+64}; wave quad owns
// key quarter. KV staged per 32-key chunk into private LDS as PACKED BF16
// (2 KB f32 -> 1 KB bf16): per key 2x ds_read_b128 instead of 4 (LDS pipe was
// the R7 bottleneck). Unpack = shift/and (CSE'd across the 2 queries).
// No barriers in the main loop (same-wave DS ordering).
// ---------------------------------------------------------------------------
__global__ __launch_bounds__(256) void k_attn(
    const float* __restrict__ qbuf,
    const float* __restrict__ kvbuf,
    const float* __restrict__ relw,
    const float* __restrict__ relh,
    float* __restrict__ apre)
{
    // [0,4096): lAw[32][128]; [4096,5120): bf16 stage (4 waves x 256 dwords)
    // after main loop: [0,4608) reused as reduction buffer
    __shared__ __align__(16) float smem[5120];

    int tid = threadIdx.x;
    int lane = tid & 63, quad = tid >> 6;
    int bn = blockIdx.x >> 3, qcv = blockIdx.x & 7;

    // ---- fill lAw: thread covers query qi = tid&127, rows (tid>>7)*16.. ----
    {
        int qi = tid & 127;
        int r0 = (tid >> 7) * 16;
        int iqf = qcv * 128 + qi;
        int wf = iqf & 31;
        const float* qpf = qbuf + (bn * 1024 + iqf) * 8;
        float4 fa = *(const float4*)qpf;
        float4 fb = *(const float4*)(qpf + 4);
        #pragma unroll
        for (int r = r0; r < r0 + 16; ++r)
            smem[r * 128 + qi] = dot8(fa, fb, relw + (r - wf + 31) * 8);
    }

    int iq0 = qcv * 128 + lane;
    int iq1 = iq0 + 64;
    int h0 = iq0 >> 5, h1 = iq1 >> 5;
    const float* qp0 = qbuf + (bn * 1024 + iq0) * 8;
    const float* qp1 = qbuf + (bn * 1024 + iq1) * 8;
    float4 q0a = *(const float4*)qp0, q0b = *(const float4*)(qp0 + 4);
    float4 q1a = *(const float4*)qp1, q1b = *(const float4*)(qp1 + 4);

    __syncthreads();

    float acc0[8] = {0,0,0,0,0,0,0,0};
    float acc1[8] = {0,0,0,0,0,0,0,0};
    float l0 = 0.f, l1 = 0.f;

    const float4* gkv = (const float4*)(kvbuf + bn * 16384 + quad * 4096);
    unsigned int* sbase = (unsigned int*)(smem + 4096) + quad * 256;
    float4 p0 = gkv[lane];
    float4 p1 = gkv[64 + lane];

    for (int c = 0; c < 8; ++c) {
        // pack this chunk to bf16 and stage (floats 4L..4L+3 -> dwords 2L..2L+1)
        ((uint2*)sbase)[lane]      = make_uint2(bfpack2(p0.x, p0.y), bfpack2(p0.z, p0.w));
        ((uint2*)sbase)[64 + lane] = make_uint2(bfpack2(p1.x, p1.y), bfpack2(p1.z, p1.w));
        if (c < 7) {                         // prefetch next chunk into regs
            p0 = gkv[(c + 1) * 128 + lane];
            p1 = gkv[(c + 1) * 128 + 64 + lane];
        }
        int t = quad * 8 + c;                // j2 row (constant per chunk)
        float ah0 = dot8(q0a, q0b, relh + (t - h0 + 31) * 8);
        float ah1 = dot8(q1a, q1b, relh + (t - h1 + 31) * 8);

        #pragma unroll 4
        for (int r = 0; r < 32; ++r) {
            const uint4* kp = (const uint4*)(sbase + r * 8);
            uint4 uk = kp[0], uv = kp[1];
            float k0 = BFLO(uk.x), k1 = BFHI(uk.x), k2 = BFLO(uk.y), k3 = BFHI(uk.y);
            float k4 = BFLO(uk.z), k5 = BFHI(uk.z), k6 = BFLO(uk.w), k7 = BFHI(uk.w);

            float s0 = smem[r * 128 + lane] + ah0 +
                q0a.x*k0 + q0a.y*k1 + q0a.z*k2 + q0a.w*k3 +
                q0b.x*k4 + q0b.y*k5 + q0b.z*k6 + q0b.w*k7;
            float s1 = smem[r * 128 + 64 + lane] + ah1 +
                q1a.x*k0 + q1a.y*k1 + q1a.z*k2 + q1a.w*k3 +
                q1b.x*k4 + q1b.y*k5 + q1b.z*k6 + q1b.w*k7;
            float pe0 = __expf(s0);
            float pe1 = __expf(s1);
            l0 += pe0; l1 += pe1;

            float v0 = BFLO(uv.x), v1 = BFHI(uv.x), v2 = BFLO(uv.y), v3 = BFHI(uv.y);
            float v4 = BFLO(uv.z), v5 = BFHI(uv.z), v6 = BFLO(uv.w), v7 = BFHI(uv.w);
            acc0[0] = fmaf(pe0, v0, acc0[0]); acc0[1] = fmaf(pe0, v1, acc0[1]);
            acc0[2] = fmaf(pe0, v2, acc0[2]); acc0[3] = fmaf(pe0, v3, acc0[3]);
            acc0[4] = fmaf(pe0, v4, acc0[4]); acc0[5] = fmaf(pe0, v5, acc0[5]);
            acc0[6] = fmaf(pe0, v6, acc0[6]); acc0[7] = fmaf(pe0, v7, acc0[7]);
            acc1[0] = fmaf(pe1, v0, acc1[0]); acc1[1] = fmaf(pe1, v1, acc1[1]);
            acc1[2] = fmaf(pe1, v2, acc1[2]); acc1[3] = fmaf(pe1, v3, acc1[3]);
            acc1[4] = fmaf(pe1, v4, acc1[4]); acc1[5] = fmaf(pe1, v5, acc1[5]);
            acc1[6] = fmaf(pe1, v6, acc1[6]); acc1[7] = fmaf(pe1, v7, acc1[7]);
        }
    }

    __syncthreads();   // all waves done with lAw/stage -> reuse as red buffer
    #pragma unroll
    for (int d = 0; d < 8; ++d) {
        smem[d * 256 + tid] = acc0[d];
        smem[(9 + d) * 256 + tid] = acc1[d];
    }
    smem[8 * 256 + tid] = l0;
    smem[17 * 256 + tid] = l1;
    __syncthreads();

    if (tid < 128) {
        int ln = tid & 63;
        int sb = (tid < 64) ? 0 : 9;
        float l = smem[(sb + 8) * 256 + ln]       + smem[(sb + 8) * 256 + ln + 64] +
                  smem[(sb + 8) * 256 + ln + 128] + smem[(sb + 8) * 256 + ln + 192];
        float inv = 1.0f / l;
        int b = bn >> 3, n = bn & 7;
        float* ap = apre + (b * 64 + n * 8) * 1024 + qcv * 128 + tid;
        #pragma unroll
        for (int d = 0; d < 8; ++d) {
            float av = smem[(sb + d) * 256 + ln]       + smem[(sb + d) * 256 + ln + 64] +
                       smem[(sb + d) * 256 + ln + 128] + smem[(sb + d) * 256 + ln + 192];
            ap[d * 1024] = av * inv;
        }
    }
}

// ---------------------------------------------------------------------------
// Kernel 3: fused output (f32). grid = 512 blocks:
//   blk <  256: 3x3 conv. decode b(8) x rg(2) x og(16); oc = og*4..+3.
//     Thread = (row 16, colpair 16): 2 adjacent cols -> each w-b128 read
//     serves 8 FMAs; x window 3x4 shared across the 2 positions.
//     x staged per 8-channel chunk: [8][18 rows][34 cols].
//   blk >= 256: attn 1x1 proj. decode b(8) x rg(4) x og(8); oc 64+og*8..
// ---------------------------------------------------------------------------
__global__ __launch_bounds__(256) void k_out(
    const float* __restrict__ xpad,
    const float* __restrict__ wconv,
    const float* __restrict__ bconv,
    const float* __restrict__ wattn,
    const float* __restrict__ battn,
    const float* __restrict__ apre,
    float* __restrict__ out)
{
    __shared__ __align__(16) float wl[2304];     // conv: [576 ct][4 g]
    __shared__ __align__(16) float xl[8 * 612];  // conv: [8 cc][18 r][34 c]
    __shared__ float bl[8];

    int blk = blockIdx.x;
    int tid = threadIdx.x;

    if (blk < 256) {
        int b = blk >> 5, rem = blk & 31, rg = rem >> 4, og = rem & 15;
        int oc0 = og * 4;
        int R0 = rg * 16;                   // out-row base
        for (int i = tid; i < 2304; i += 256) {
            int g = i & 3, ct = i >> 2;
            wl[i] = wconv[(oc0 + g) * 576 + ct];
        }
        if (tid < 4) bl[tid] = bconv[oc0 + tid];

        int rl = tid >> 4;                  // 0..15 local out row
        int c0 = (tid & 15) * 2;            // even col
        float acc0[4] = {0.f, 0.f, 0.f, 0.f};
        float acc1[4] = {0.f, 0.f, 0.f, 0.f};
        const float* xsrc = xpad + b * 64 * 1156 + R0 * 34;

        for (int ch = 0; ch < 8; ++ch) {
            __syncthreads();                // prev readers done (+wl visible)
            for (int i = tid; i < 4896; i += 256) {
                int cc = i / 612, r2 = i % 612;
                xl[i] = xsrc[(ch * 8 + cc) * 1156 + r2];
            }
            __syncthreads();
            for (int cc = 0; cc < 8; ++cc) {
                const float* xc = xl + cc * 612 + rl * 34 + c0;
                float xv[3][4];
                #pragma unroll
                for (int dr = 0; dr < 3; ++dr) {
                    #pragma unroll
                    for (int dc = 0; dc < 4; ++dc)
                        xv[dr][dc] = xc[dr * 34 + dc];
                }
                const float4* wc = (const float4*)(wl + (ch * 8 + cc) * 36);
                #pragma unroll
                for (int t = 0; t < 9; ++t) {
                    float4 wv = wc[t];      // broadcast b128: 4 oc weights
                    float x0 = xv[t / 3][t % 3];
                    float x1 = xv[t / 3][t % 3 + 1];
                    acc0[0] = fmaf(wv.x, x0, acc0[0]); acc1[0] = fmaf(wv.x, x1, acc1[0]);
                    acc0[1] = fmaf(wv.y, x0, acc0[1]); acc1[1] = fmaf(wv.y, x1, acc1[1]);
                    acc0[2] = fmaf(wv.z, x0, acc0[2]); acc1[2] = fmaf(wv.z, x1, acc1[2]);
                    acc0[3] = fmaf(wv.w, x0, acc0[3]); acc1[3] = fmaf(wv.w, x1, acc1[3]);
                }
            }
        }
        int p0 = (R0 + rl) * 32 + c0;
        #pragma unroll
        for (int g = 0; g < 4; ++g) {
            float2 o2 = make_float2(acc0[g] + bl[g], acc1[g] + bl[g]);
            *(float2*)(out + (b * 128 + oc0 + g) * 1024 + p0) = o2;
        }
    } else {
        int pb = blk - 256;
        int b = pb >> 5, rem = pb & 31, rg = rem >> 3, og = rem & 7;
        int o0 = og * 8;
        for (int i = tid; i < 512; i += 256) {
            int g = i & 7, c = i >> 3;
            wl[c * 8 + g] = wattn[(o0 + g) * 64 + c];
        }
        if (tid < 8) bl[tid] = battn[o0 + tid];
        __syncthreads();

        int p = rg * 256 + tid;
        float acc[8] = {0,0,0,0,0,0,0,0};
        const float* ap = apre + b * 65536 + p;
        #pragma unroll 4
        for (int c = 0; c < 64; ++c) {
            float xv = ap[c * 1024];
            const float4* wv4 = (const float4*)(wl + c * 8);
            float4 wa = wv4[0], wb = wv4[1];  // broadcast
            acc[0] = fmaf(wa.x, xv, acc[0]); acc[1] = fmaf(wa.y, xv, acc[1]);
            acc[2] = fmaf(wa.z, xv, acc[2]); acc[3] = fmaf(wa.w, xv, acc[3]);
            acc[4] = fmaf(wb.x, xv, acc[4]); acc[5] = fmaf(wb.y, xv, acc[5]);
            acc[6] = fmaf(wb.z, xv, acc[6]); acc[7] = fmaf(wb.w, xv, acc[7]);
        }
        #pragma unroll
        for (int g = 0; g < 8; ++g)
            out[(b * 128 + 64 + o0 + g) * 1024 + p] = acc[g] + bl[g];
    }
}

// ---------------------------------------------------------------------------
extern "C" void kernel_launch(void* const* d_in, const int* in_sizes, int n_in,
                              void* d_out, int out_size, void* d_ws, size_t ws_size,
                              hipStream_t stream)
{
    float* ws = (float*)d_ws;
    float* out = (float*)d_out;

    k_prep<<<(WEND + 255) / 256, 256, 0, stream>>>(
        (const float*)d_in[0], (const float*)d_in[1], (const float*)d_in[2],
        (const float*)d_in[3], (const float*)d_in[4], (const float*)d_in[5],
        (const float*)d_in[6], (const float*)d_in[7], (const float*)d_in[8], ws);
    k_qkv<<<512, 256, 0, stream>>>(
        ws + XPAD, ws + WQKV, ws + BQKV, ws + QBUF, ws + KVBUF);
    k_attn<<<512, 256, 0, stream>>>(
        ws + QBUF, ws + KVBUF, ws + RELW, ws + RELH, ws + APRE);
    k_out<<<512, 256, 0, stream>>>(
        ws + XPAD, ws + WCONV, ws + BCONV, ws + WATTN, ws + BATTN, ws + APRE, out);
}